// Round 3
// baseline (245.700 us; speedup 1.0000x reference)
//
#include <hip/hip_runtime.h>

// GRAPE axis-collapse: all 20 steps rotate about X, so scan == one rotation by
// Theta = sum(a_k)*DT/2.  Per column:
//   real0' = c*r0 + s*i1   imag0' = c*i0 - s*r1
//   real1' = c*r1 + s*i0   imag1' = c*i1 - s*r0
// Pure stream: 128 MiB in + 128 MiB out. R3 = R2 with native ext_vector_type
// (clang's nontemporal builtin rejects HIP_vector_type float4).

#define BLOCK 256
#define UNROLL 4

typedef float v4f __attribute__((ext_vector_type(4)));

__global__ __launch_bounds__(BLOCK) void grape_kernel(
    const float* __restrict__ amps, int nsteps,
    const v4f* __restrict__ sreal, const v4f* __restrict__ simag,
    v4f* __restrict__ out, long long B4) {
    // wave-uniform scalar prologue
    float theta = 0.0f;
    for (int k = 0; k < nsteps; ++k) theta += amps[k];
    theta *= 0.5f / (float)nsteps;  // DT/2, GATE_TIME = 1.0
    const float c = cosf(theta);
    const float s = sinf(theta);

    const long long nth = (long long)gridDim.x * BLOCK;
    const long long tid = (long long)blockIdx.x * BLOCK + threadIdx.x;

    const v4f* __restrict__ r0p = sreal;
    const v4f* __restrict__ r1p = sreal + B4;
    const v4f* __restrict__ i0p = simag;
    const v4f* __restrict__ i1p = simag + B4;
    v4f* o0 = out;
    v4f* o1 = out + B4;
    v4f* o2 = out + 2 * B4;
    v4f* o3 = out + 3 * B4;

    // Issue all 16 loads before any dependent use.
    v4f r0[UNROLL], r1[UNROLL], i0[UNROLL], i1[UNROLL];
#pragma unroll
    for (int u = 0; u < UNROLL; ++u) {
        long long j = tid + (long long)u * nth;
        long long jj = (j < B4) ? j : tid;  // clamp keeps loads in-bounds
        r0[u] = r0p[jj];
        r1[u] = r1p[jj];
        i0[u] = i0p[jj];
        i1[u] = i1p[jj];
    }

#pragma unroll
    for (int u = 0; u < UNROLL; ++u) {
        long long j = tid + (long long)u * nth;
        if (j >= B4) break;
        v4f a = c * r0[u] + s * i1[u];
        v4f b = c * r1[u] + s * i0[u];
        v4f d = c * i0[u] - s * r1[u];
        v4f e = c * i1[u] - s * r0[u];
        __builtin_nontemporal_store(a, &o0[j]);
        __builtin_nontemporal_store(b, &o1[j]);
        __builtin_nontemporal_store(d, &o2[j]);
        __builtin_nontemporal_store(e, &o3[j]);
    }
}

extern "C" void kernel_launch(void* const* d_in, const int* in_sizes, int n_in,
                              void* d_out, int out_size, void* d_ws, size_t ws_size,
                              hipStream_t stream) {
    const float* amps  = (const float*)d_in[0];
    const float* sreal = (const float*)d_in[1];
    const float* simag = (const float*)d_in[2];
    float* out = (float*)d_out;

    int nsteps = in_sizes[0];
    long long B  = (long long)in_sizes[1] / 2;  // state_real is [2, B]
    long long B4 = B / 4;                       // float4 columns per row

    long long per_block = (long long)BLOCK * UNROLL;
    long long grid = (B4 + per_block - 1) / per_block;  // 2048 for B=8388608

    grape_kernel<<<(dim3)(unsigned)grid, BLOCK, 0, stream>>>(
        amps, nsteps, (const v4f*)sreal, (const v4f*)simag,
        (v4f*)out, B4);
}